// Round 13
// baseline (518.787 us; speedup 1.0000x reference)
//
#include <hip/hip_runtime.h>
#include <stdint.h>

typedef int v4i __attribute__((ext_vector_type(4)));

#define TOKENS 4096   // B*S
#define HDIM   2048   // H
#define IDIM   8192   // I
#define WN     16777216  // elements per weight tensor (I*H == H*I) = 2^24
#define NBLK   512       // partial blocks per tensor (each = 256 leaves of 128)
#define BANDP  5e-7f     // half-split insurance band around the 0.5 boundary

#define MFMA_I8 __builtin_amdgcn_mfma_i32_16x16x64_i8

// ---- async global->LDS, 16B per lane (dest = uniform base + lane*16) ----
static __device__ __forceinline__ void gload_lds16(const void* g, void* l) {
  __builtin_amdgcn_global_load_lds(
      (const __attribute__((address_space(1))) void*)(unsigned long long)(uintptr_t)g,
      (__attribute__((address_space(3))) void*)(unsigned)(uintptr_t)l,
      16, 0, 0);
}

static __device__ __forceinline__ double wsum64d(double v) {
#pragma unroll
  for (int m = 32; m; m >>= 1) v += __shfl_xor(v, m, 64);
  return v;
}
static __device__ __forceinline__ double wmax64d(double v) {
#pragma unroll
  for (int m = 32; m; m >>= 1) v = fmax(v, __shfl_xor(v, m, 64));
  return v;
}
static __device__ __forceinline__ float wmax64f(float v) {
#pragma unroll
  for (int m = 32; m; m >>= 1) v = fmaxf(v, __shfl_xor(v, m, 64));
  return v;
}

// f32 quant decision (single f32 product rounding, like jax/np float32)
static __device__ __forceinline__ int q8f(float v, float s, float lo, float hi) {
  float p = v * s;
  return (int)fminf(fmaxf(rintf(p), lo), hi);
}
static __device__ __forceinline__ uint32_t packq_f(float4 v, float s) {
  int a = q8f(v.x, s, -128.f, 127.f);
  int b = q8f(v.y, s, -128.f, 127.f);
  int c = q8f(v.z, s, -128.f, 127.f);
  int d = q8f(v.w, s, -128.f, 127.f);
  return (uint32_t)((a & 255) | ((b & 255) << 8) | ((c & 255) << 16) | ((d & 255) << 24));
}

// ---- kernel 1a: numpy-style f32 pairwise partial sums of |w| ----
__global__ __launch_bounds__(256) void wsum_leaf(const float* __restrict__ wg,
                                                 const float* __restrict__ wu,
                                                 const float* __restrict__ wd,
                                                 float* __restrict__ part) {
  const float* w = blockIdx.y == 0 ? wg : (blockIdx.y == 1 ? wu : wd);
  int tid = threadIdx.x;
  const float4* w4 = (const float4*)w;
  size_t base4 = ((size_t)blockIdx.x * 256 + tid) * 32;  // 32 float4 = 128 elems
  float4 p = w4[base4], q = w4[base4 + 1];
  float r0 = fabsf(p.x), r1 = fabsf(p.y), r2 = fabsf(p.z), r3 = fabsf(p.w);
  float r4 = fabsf(q.x), r5 = fabsf(q.y), r6 = fabsf(q.z), r7 = fabsf(q.w);
  for (int i = 2; i < 32; i += 2) {
    float4 a = w4[base4 + i], b = w4[base4 + i + 1];
    r0 += fabsf(a.x); r1 += fabsf(a.y); r2 += fabsf(a.z); r3 += fabsf(a.w);
    r4 += fabsf(b.x); r5 += fabsf(b.y); r6 += fabsf(b.z); r7 += fabsf(b.w);
  }
  float leaf = ((r0 + r1) + (r2 + r3)) + ((r4 + r5) + (r6 + r7));
  __shared__ float A[256], B[256];
  A[tid] = leaf;
  __syncthreads();
  float* src = A; float* dst = B;
  for (int n = 128; n >= 1; n >>= 1) {   // adjacent-pair tree, 8 levels
    if (tid < n) dst[tid] = src[2 * tid] + src[2 * tid + 1];
    __syncthreads();
    float* t = src; src = dst; dst = t;
  }
  if (tid == 0) part[blockIdx.y * NBLK + blockIdx.x] = src[0];
}

// ---- kernel 1b: combine 512 partials per tensor (adjacent-pair tree) ----
__global__ __launch_bounds__(256) void wsum_final(const float* __restrict__ part,
                                                  float* __restrict__ wsc) {
  int t = blockIdx.x, tid = threadIdx.x;
  __shared__ float A[512], B[256];
  A[tid] = part[t * NBLK + tid];
  A[tid + 256] = part[t * NBLK + tid + 256];
  __syncthreads();
  float* src = A; float* dst = B;
  for (int n = 256; n >= 1; n >>= 1) {   // 512 -> 1, 9 levels
    if (tid < n) dst[tid] = src[2 * tid] + src[2 * tid + 1];
    __syncthreads();
    float* tmp = src; src = dst; dst = tmp;
  }
  if (tid == 0) {
    float mean32 = src[0] / (float)WN;       // exact (/2^24)
    float m32 = fmaxf(mean32, 1e-5f);        // np.clip float32
    float s32 = 1.0f / m32;
    wsc[t] = s32;
    wsc[3 + t] = 1.0f / s32;                 // fl32(1/s) dequant value
  }
}

// ---- kernel 2: ternary weight quant, doubled-scale {0,±1,±2};
//      boundary band -> ±1 (i.e. half-weight insurance) ----
__global__ __launch_bounds__(256) void wquant_kernel(const float* __restrict__ wg,
                                                     const float* __restrict__ wu,
                                                     const float* __restrict__ wd,
                                                     const float* __restrict__ wsc,
                                                     int8_t* __restrict__ qg,
                                                     int8_t* __restrict__ qu,
                                                     int8_t* __restrict__ qd) {
  int t = blockIdx.y;
  const float* w = t == 0 ? wg : (t == 1 ? wu : wd);
  int8_t* q = t == 0 ? qg : (t == 1 ? qu : qd);
  float s32 = wsc[t];
  const float4* w4 = (const float4*)w;
  uint32_t* q4 = (uint32_t*)q;
  const int n4 = WN / 4;
  for (int i = blockIdx.x * 256 + threadIdx.x; i < n4; i += gridDim.x * 256) {
    float4 v = w4[i];
    float vv[4] = {v.x, v.y, v.z, v.w};
    int o[4];
#pragma unroll
    for (int j = 0; j < 4; ++j) {
      float pf = fabsf(vv[j]) * s32;               // |fl32(w*s)|
      int q2 = 2 * (int)fminf(rintf(pf), 1.0f);    // 0 or 2 (doubled scale)
      if (fabsf(pf - 0.5f) < BANDP) q2 = 1;        // boundary -> half weight
      o[j] = (vv[j] < 0.0f) ? -q2 : q2;
    }
    q4[i] = (uint32_t)((o[0] & 255) | ((o[1] & 255) << 8) |
                       ((o[2] & 255) << 16) | ((o[3] & 255) << 24));
  }
}

// ---- kernel 3: per-token activation quant of x (float32 decisions) ----
__global__ __launch_bounds__(256) void xquant_kernel(const float* __restrict__ x,
                                                     int8_t* __restrict__ qx,
                                                     double* __restrict__ axd) {
  int row = blockIdx.x, tid = threadIdx.x;
  const float4* xr = (const float4*)(x + (size_t)row * HDIM);
  float4 v0 = xr[tid], v1 = xr[tid + 256];
  float m = fmaxf(fmaxf(fmaxf(fabsf(v0.x), fabsf(v0.y)), fmaxf(fabsf(v0.z), fabsf(v0.w))),
                  fmaxf(fmaxf(fabsf(v1.x), fabsf(v1.y)), fmaxf(fabsf(v1.z), fabsf(v1.w))));
  m = wmax64f(m);
  __shared__ float red[4];
  int wid = tid >> 6, lane = tid & 63;
  if (lane == 0) red[wid] = m;
  __syncthreads();
  float mm = fmaxf(fmaxf(red[0], red[1]), fmaxf(red[2], red[3]));
  float c32 = fmaxf(mm, 1e-5f);
  float s32 = 127.0f / c32;
  if (tid == 0) axd[row] = 1.0 / (double)s32;
  uint32_t* q4 = (uint32_t*)(qx + (size_t)row * HDIM);
  q4[tid] = packq_f(v0, s32);
  q4[tid + 256] = packq_f(v1, s32);
}

// ---- kernel 4: fused GEMM1 (gate+up), barrier-light 3-buffer pipeline ----
// 512 threads, 8 waves (2M x 4N), tile 128x128, per-wave 64x32.
// 3-buffer LDS (3 x 24KB = 72KB, dynamic). Phases read ONLY c0; gloads write
// ONLY c2 (disjoint) -> NO mid-iter barriers needed. ONE vmcnt(3)+s_barrier
// per K-iter protects rotation (own t+1 batch landed; all reads of c0 done
// before it becomes next iter's write target). Compiler owns ds_read->MFMA
// scheduling (fine-grained lgkmcnt, m97) and waves drift to feed MFMA pipe.
__global__ __launch_bounds__(512, 4) void gemm1_kernel(const int8_t* __restrict__ qx,
                                                       const int8_t* __restrict__ qg,
                                                       const int8_t* __restrict__ qu,
                                                       const float* __restrict__ wsc,
                                                       const double* __restrict__ axd,
                                                       float* __restrict__ h) {
  extern __shared__ char lds[];
  int tid = threadIdx.x, wid = tid >> 6, lane = tid & 63;
  int l15 = lane & 15, lgp = lane >> 4;
  int wr = wid >> 2, wc = wid & 3;  // 2 x 4 waves
  // L2-aware XCD swizzle: xcd = flat&7 owns n-tiles [8*xcd, 8*xcd+8), all m.
  int flat = blockIdx.y * 64 + blockIdx.x;
  int xcd = flat & 7, local = flat >> 3;       // local in [0,256)
  int mt = local >> 3, nl = local & 7;
  int m0 = mt * 128, n0 = (xcd * 8 + nl) * 128;
  const int8_t* bA = qx + (size_t)m0 * HDIM;
  const int8_t* bG = qg + (size_t)n0 * HDIM;
  const int8_t* bU = qu + (size_t)n0 * HDIM;

  v4i accg[4][2], accu[4][2];
  v4i vzero = {0, 0, 0, 0};
#pragma unroll
  for (int i = 0; i < 4; ++i)
#pragma unroll
    for (int j = 0; j < 2; ++j) { accg[i][j] = vzero; accu[i][j] = vzero; }

  int aoff[4], goff[2], uoff[2];
#pragma unroll
  for (int i = 0; i < 4; ++i)
    aoff[i] = lgp * 2048 + (wr * 64 + i * 16 + l15) * 16;
#pragma unroll
  for (int i = 0; i < 2; ++i) {
    goff[i] = 8192 + lgp * 2048 + (wc * 32 + i * 16 + l15) * 16;
    uoff[i] = goff[i] + 8192;
  }

  int srow = tid & 127, sslab = tid >> 7;
  const size_t rA = (size_t)srow * HDIM;
  int sdst = sslab * 2048 + srow * 16;  // within-buffer staging dest

  const int NT = HDIM / 64;  // 32
  // prologue: stage tiles 0,1 into buffers 0,1
  {
    size_t k0 = (size_t)sslab * 16;
    gload_lds16(bA + rA + k0, lds + sdst);
    gload_lds16(bG + rA + k0, lds + sdst + 8192);
    gload_lds16(bU + rA + k0, lds + sdst + 16384);
    size_t k1 = 64 + (size_t)sslab * 16;
    gload_lds16(bA + rA + k1, lds + 24576 + sdst);
    gload_lds16(bG + rA + k1, lds + 24576 + sdst + 8192);
    gload_lds16(bU + rA + k1, lds + 24576 + sdst + 16384);
  }
  asm volatile("s_waitcnt vmcnt(3)" ::: "memory");  // tile-0 batch landed
  __builtin_amdgcn_s_barrier();
  __builtin_amdgcn_sched_barrier(0);

  int c0 = 0, c1 = 24576, c2 = 49152;  // read buf, next buf, write buf
  for (int t = 0; t < NT; ++t) {
    const bool pf = (t + 2 < NT);
    size_t koff = (size_t)(t + 2) * 64 + sslab * 16;
    // free-flowing body: reads from c0, prefetch into c2, MFMAs.
    v4i a0 = *(const v4i*)(lds + c0 + aoff[0]);
    v4i a1 = *(const v4i*)(lds + c0 + aoff[1]);
    v4i bg0 = *(const v4i*)(lds + c0 + goff[0]);
    v4i bg1 = *(const v4i*)(lds + c0 + goff[1]);
    if (pf) gload_lds16(bA + rA + koff, lds + c2 + sdst);
    accg[0][0] = MFMA_I8(a0, bg0, accg[0][0], 0, 0, 0);
    accg[0][1] = MFMA_I8(a0, bg1, accg[0][1], 0, 0, 0);
    accg[1][0] = MFMA_I8(a1, bg0, accg[1][0], 0, 0, 0);
    accg[1][1] = MFMA_I8(a1, bg1, accg[1][1], 0, 0, 0);
    v4i a2 = *(const v4i*)(lds + c0 + aoff[2]);
    v4i a3 = *(const v4i*)(lds + c0 + aoff[3]);
    if (pf) gload_lds16(bG + rA + koff, lds + c2 + sdst + 8192);
    accg[2][0] = MFMA_I8(a2, bg0, accg[2][0], 0, 0, 0);
    accg[2][1] = MFMA_I8(a2, bg1, accg[2][1], 0, 0, 0);
    accg[3][0] = MFMA_I8(a3, bg0, accg[3][0], 0, 0, 0);
    accg[3][1] = MFMA_I8(a3, bg1, accg[3][1], 0, 0, 0);
    v4i bu0 = *(const v4i*)(lds + c0 + uoff[0]);
    v4i bu1 = *(const v4i*)(lds + c0 + uoff[1]);
    if (pf) gload_lds16(bU + rA + koff, lds + c2 + sdst + 16384);
    accu[0][0] = MFMA_I8(a0, bu0, accu[0][0], 0, 0, 0);
    accu[0][1] = MFMA_I8(a0, bu1, accu[0][1], 0, 0, 0);
    accu[1][0] = MFMA_I8(a1, bu0, accu[1][0], 0, 0, 0);
    accu[1][1] = MFMA_I8(a1, bu1, accu[1][1], 0, 0, 0);
    accu[2][0] = MFMA_I8(a2, bu0, accu[2][0], 0, 0, 0);
    accu[2][1] = MFMA_I8(a2, bu1, accu[2][1], 0, 0, 0);
    accu[3][0] = MFMA_I8(a3, bu0, accu[3][0], 0, 0, 0);
    accu[3][1] = MFMA_I8(a3, bu1, accu[3][1], 0, 0, 0);
    // single rotation fence: own t+1 batch landed; all c0 reads done block-wide
    if (pf)
      asm volatile("s_waitcnt vmcnt(3)" ::: "memory");
    else
      asm volatile("s_waitcnt vmcnt(0)" ::: "memory");
    __builtin_amdgcn_s_barrier();
    __builtin_amdgcn_sched_barrier(0);
    int tmp = c0; c0 = c1; c1 = c2; c2 = tmp;  // rotate buffers
  }

  double mg = 0.5 * (double)wsc[3 + 0];  // halved: doubled-scale weights
  double mu = 0.5 * (double)wsc[3 + 1];
#pragma unroll
  for (int mi = 0; mi < 4; ++mi) {
#pragma unroll
    for (int rg = 0; rg < 4; ++rg) {
      int grow = m0 + wr * 64 + mi * 16 + lgp * 4 + rg;
      double axr = axd[grow];
      double sg = axr * mg, su = axr * mu;
#pragma unroll
      for (int ni = 0; ni < 2; ++ni) {
        int gcol = n0 + wc * 32 + ni * 16 + l15;
        double g = (double)accg[mi][ni][rg] * sg;
        double u = (double)accu[mi][ni][rg] * su;
        double sig = 1.0 / (1.0 + exp(-g));
        h[(size_t)grow * IDIM + gcol] = (float)((g * sig) * u);
      }
    }
  }
}

// ---- kernel 5: per-row rms-norm + activation quant of h ----
__global__ __launch_bounds__(256) void hquant_kernel(const float* __restrict__ h,
                                                     const float* __restrict__ lnw,
                                                     double* __restrict__ ahd,
                                                     int8_t* __restrict__ qh) {
  int row = blockIdx.x, tid = threadIdx.x;
  const float4* hr = (const float4*)(h + (size_t)row * IDIM);
  const float4* lw4 = (const float4*)lnw;
  float4 hv[8], wv[8];
  double ssq = 0.0;
#pragma unroll
  for (int i = 0; i < 8; ++i) {
    hv[i] = hr[tid + i * 256];
    wv[i] = lw4[tid + i * 256];
    ssq += (double)hv[i].x * hv[i].x + (double)hv[i].y * hv[i].y +
           (double)hv[i].z * hv[i].z + (double)hv[i].w * hv[i].w;
  }
  ssq = wsum64d(ssq);
  __shared__ double redd[4];
  __shared__ double redm[4];
  int wid = tid >> 6, lane = tid & 63;
  if (lane == 0) redd[wid] = ssq;
  __syncthreads();
  double tot = redd[0] + redd[1] + redd[2] + redd[3];
  double rd = 1.0 / sqrt(tot * (1.0 / (double)IDIM) + 1e-6);
  double mx = 0.0;
#pragma unroll
  for (int i = 0; i < 8; ++i) {
    double y0 = (double)wv[i].x * ((double)hv[i].x * rd);
    double y1 = (double)wv[i].y * ((double)hv[i].y * rd);
    double y2 = (double)wv[i].z * ((double)hv[i].z * rd);
    double y3 = (double)wv[i].w * ((double)hv[i].w * rd);
    mx = fmax(mx, fmax(fmax(fabs(y0), fabs(y1)), fmax(fabs(y2), fabs(y3))));
  }
  mx = wmax64d(mx);
  if (lane == 0) redm[wid] = mx;
  __syncthreads();
  double mm = fmax(fmax(redm[0], redm[1]), fmax(redm[2], redm[3]));
  float c32 = fmaxf((float)mm, 1e-5f);
  float s32 = 127.0f / c32;
  double sd = (double)s32;
  if (tid == 0) ahd[row] = 1.0 / (double)s32;
  uint32_t* q4 = (uint32_t*)(qh + (size_t)row * IDIM);
#pragma unroll
  for (int i = 0; i < 8; ++i) {
    double y0 = (double)wv[i].x * ((double)hv[i].x * rd);
    double y1 = (double)wv[i].y * ((double)hv[i].y * rd);
    double y2 = (double)wv[i].z * ((double)hv[i].z * rd);
    double y3 = (double)wv[i].w * ((double)hv[i].w * rd);
    int a = (int)fmin(fmax(rint(y0 * sd), -128.0), 127.0);
    int b = (int)fmin(fmax(rint(y1 * sd), -128.0), 127.0);
    int c = (int)fmin(fmax(rint(y2 * sd), -128.0), 127.0);
    int d = (int)fmin(fmax(rint(y3 * sd), -128.0), 127.0);
    q4[tid + i * 256] = (uint32_t)((a & 255) | ((b & 255) << 8) | ((c & 255) << 16) | ((d & 255) << 24));
  }
}

// ---- kernel 6: GEMM2 (down proj), barrier-light 3-buffer pipeline ----
// 512 threads, tile 128x128; 3-buffer dynamic LDS = 48KB; one vmcnt(2)+barrier
// per K-iter (same disjoint-buffer argument as gemm1).
__global__ __launch_bounds__(512, 4) void gemm2_kernel(const int8_t* __restrict__ qh,
                                                       const int8_t* __restrict__ qd,
                                                       const float* __restrict__ wsc,
                                                       const double* __restrict__ ahd,
                                                       float* __restrict__ out) {
  extern __shared__ char lds[];
  int tid = threadIdx.x, wid = tid >> 6, lane = tid & 63;
  int l15 = lane & 15, lgp = lane >> 4;
  int wr = wid >> 2, wc = wid & 3;
  int flat = blockIdx.y * 16 + blockIdx.x;     // [0,512)
  int xcd = flat & 7, local = flat >> 3;       // local in [0,64)
  int mt = xcd * 4 + (local >> 4), nt = local & 15;
  int m0 = mt * 128, n0 = nt * 128;
  const int8_t* bA = qh + (size_t)m0 * IDIM;
  const int8_t* bB = qd + (size_t)n0 * IDIM;

  v4i acc[4][2];
  v4i vzero = {0, 0, 0, 0};
#pragma unroll
  for (int i = 0; i < 4; ++i)
#pragma unroll
    for (int j = 0; j < 2; ++j) acc[i][j] = vzero;

  int aoff[4], boff[2];
#pragma unroll
  for (int i = 0; i < 4; ++i)
    aoff[i] = lgp * 2048 + (wr * 64 + i * 16 + l15) * 16;
#pragma unroll
  for (int i = 0; i < 2; ++i)
    boff[i] = 8192 + lgp * 2048 + (wc * 32 + i * 16 + l15) * 16;

  int srow = tid & 127, sslab = tid >> 7;
  const size_t rA = (size_t)srow * IDIM;
  int sdst = sslab * 2048 + srow * 16;

  const int NT = IDIM / 64;  // 128
  {
    size_t k0 = (size_t)sslab * 16;
    gload_lds16(bA + rA + k0, lds + sdst);
    gload_lds16(bB + rA + k0, lds + sdst + 8192);
    size_t k1 = 64 + (size_t)sslab * 16;
    gload_lds16(bA + rA + k1, lds + 16384 + sdst);
    gload_lds16(bB + rA + k1, lds + 16384 + sdst + 8192);
  }
  asm volatile("s_waitcnt vmcnt(2)" ::: "memory");
  __builtin_amdgcn_s_barrier();
  __builtin_amdgcn_sched_barrier(0);

  int c0 = 0, c1 = 16384, c2 = 32768;
  for (int t = 0; t < NT; ++t) {
    const bool pf = (t + 2 < NT);
    size_t koff = (size_t)(t + 2) * 64 + sslab * 16;
    v4i a0 = *(const v4i*)(lds + c0 + aoff[0]);
    v4i a1 = *(const v4i*)(lds + c0 + aoff[1]);
    v4i b0 = *(const v4i*)(lds + c0 + boff[0]);
    v4i b1 = *(const v4i*)(lds + c0 + boff[1]);
    if (pf) gload_lds16(bA + rA + koff, lds + c2 + sdst);
    acc[0][0] = MFMA_I8(a0, b0, acc[0][0], 0, 0, 0);
    acc[0][1] = MFMA_I8(a0, b1, acc[0][1], 0, 0, 0);
    acc[1][0] = MFMA_I8(a1, b0, acc[1][0], 0, 0, 0);
    acc[1][1] = MFMA_I8(a1, b1, acc[1][1], 0, 0, 0);
    v4i a2 = *(const v4i*)(lds + c0 + aoff[2]);
    v4i a3 = *(const v4i*)(lds + c0 + aoff[3]);
    if (pf) gload_lds16(bB + rA + koff, lds + c2 + sdst + 8192);
    acc[2][0] = MFMA_I8(a2, b0, acc[2][0], 0, 0, 0);
    acc[2][1] = MFMA_I8(a2, b1, acc[2][1], 0, 0, 0);
    acc[3][0] = MFMA_I8(a3, b0, acc[3][0], 0, 0, 0);
    acc[3][1] = MFMA_I8(a3, b1, acc[3][1], 0, 0, 0);
    if (pf)
      asm volatile("s_waitcnt vmcnt(2)" ::: "memory");
    else
      asm volatile("s_waitcnt vmcnt(0)" ::: "memory");
    __builtin_amdgcn_s_barrier();
    __builtin_amdgcn_sched_barrier(0);
    int tmp = c0; c0 = c1; c1 = c2; c2 = tmp;
  }

  double md = 0.5 * (double)wsc[3 + 2];  // halved: doubled-scale weights
#pragma unroll
  for (int mi = 0; mi < 4; ++mi) {
#pragma unroll
    for (int rg = 0; rg < 4; ++rg) {
      int grow = m0 + wr * 64 + mi * 16 + lgp * 4 + rg;
      double sc = ahd[grow] * md;
#pragma unroll
      for (int ni = 0; ni < 2; ++ni) {
        int gcol = n0 + wc * 32 + ni * 16 + l15;
        out[(size_t)grow * HDIM + gcol] = (float)((double)acc[mi][ni][rg] * sc);
      }
    }
  }
}

extern "C" void kernel_launch(void* const* d_in, const int* in_sizes, int n_in,
                              void* d_out, int out_size, void* d_ws, size_t ws_size,
                              hipStream_t stream) {
  const float* x   = (const float*)d_in[0];
  const float* wg  = (const float*)d_in[1];
  const float* wu  = (const float*)d_in[2];
  const float* wd  = (const float*)d_in[3];
  const float* lnw = (const float*)d_in[4];
  float* out = (float*)d_out;
  char* ws = (char*)d_ws;

  size_t off = 0;
  auto alloc = [&](size_t b) { size_t o = off; off += (b + 255) & ~(size_t)255; return o; };
  size_t o_wsc  = alloc(8 * 4);                 // s32[3], fl32(1/s)[3]
  size_t o_part = alloc(3 * NBLK * 4);
  size_t o_axd  = alloc((size_t)TOKENS * 8);
  size_t o_ahd  = alloc((size_t)TOKENS * 8);
  size_t o_qx   = alloc((size_t)TOKENS * HDIM);
  size_t o_qg   = alloc((size_t)IDIM * HDIM);   // qh later overlays qg
  size_t o_qu   = alloc((size_t)IDIM * HDIM);
  size_t o_qd   = alloc((size_t)HDIM * IDIM);
  size_t o_h    = alloc((size_t)TOKENS * IDIM * 4);
  (void)ws_size; (void)in_sizes; (void)n_in; (void)out_size; (void)o_qu;

  float* wsc  = (float*)(ws + o_wsc);
  float* part = (float*)(ws + o_part);
  double* axd = (double*)(ws + o_axd);
  double* ahd = (double*)(ws + o_ahd);
  int8_t* qx  = (int8_t*)(ws + o_qx);
  int8_t* qg  = (int8_t*)(ws + o_qg);
  int8_t* qu  = (int8_t*)(ws + o_qu);
  int8_t* qd  = (int8_t*)(ws + o_qd);
  int8_t* qh  = (int8_t*)(ws + o_qg);  // overlay: qg/qu dead after gemm1
  float* h    = (float*)(ws + o_h);

  wsum_leaf<<<dim3(NBLK, 3), 256, 0, stream>>>(wg, wu, wd, part);
  wsum_final<<<3, 256, 0, stream>>>(part, wsc);
  wquant_kernel<<<dim3(1024, 3), 256, 0, stream>>>(wg, wu, wd, wsc, qg, qu, qd);
  xquant_kernel<<<TOKENS, 256, 0, stream>>>(x, qx, axd);
  gemm1_kernel<<<dim3(IDIM / 128, TOKENS / 128), 512, 3 * 24576, stream>>>(qx, qg, qu, wsc, axd, h);
  hquant_kernel<<<TOKENS, 256, 0, stream>>>(h, lnw, ahd, qh);
  gemm2_kernel<<<dim3(HDIM / 128, TOKENS / 128), 512, 3 * 16384, stream>>>(qh, qd, wsc, ahd, out);
}

// Round 14
// 501.176 us; speedup vs baseline: 1.0351x; 1.0351x over previous
//
#include <hip/hip_runtime.h>
#include <stdint.h>

typedef int v4i __attribute__((ext_vector_type(4)));

#define TOKENS 4096   // B*S
#define HDIM   2048   // H
#define IDIM   8192   // I
#define WN     16777216  // elements per weight tensor (I*H == H*I) = 2^24
#define NBLK   512       // partial blocks per tensor (each = 256 leaves of 128)
#define BANDP  5e-7f     // half-split insurance band around the 0.5 boundary

#define MFMA_I8 __builtin_amdgcn_mfma_i32_16x16x64_i8

// ---- async global->LDS, 16B per lane (dest = uniform base + lane*16) ----
static __device__ __forceinline__ void gload_lds16(const void* g, void* l) {
  __builtin_amdgcn_global_load_lds(
      (const __attribute__((address_space(1))) void*)(unsigned long long)(uintptr_t)g,
      (__attribute__((address_space(3))) void*)(unsigned)(uintptr_t)l,
      16, 0, 0);
}

static __device__ __forceinline__ double wsum64d(double v) {
#pragma unroll
  for (int m = 32; m; m >>= 1) v += __shfl_xor(v, m, 64);
  return v;
}
static __device__ __forceinline__ double wmax64d(double v) {
#pragma unroll
  for (int m = 32; m; m >>= 1) v = fmax(v, __shfl_xor(v, m, 64));
  return v;
}
static __device__ __forceinline__ float wmax64f(float v) {
#pragma unroll
  for (int m = 32; m; m >>= 1) v = fmaxf(v, __shfl_xor(v, m, 64));
  return v;
}

// f32 quant decision (single f32 product rounding, like jax/np float32)
static __device__ __forceinline__ int q8f(float v, float s, float lo, float hi) {
  float p = v * s;
  return (int)fminf(fmaxf(rintf(p), lo), hi);
}
static __device__ __forceinline__ uint32_t packq_f(float4 v, float s) {
  int a = q8f(v.x, s, -128.f, 127.f);
  int b = q8f(v.y, s, -128.f, 127.f);
  int c = q8f(v.z, s, -128.f, 127.f);
  int d = q8f(v.w, s, -128.f, 127.f);
  return (uint32_t)((a & 255) | ((b & 255) << 8) | ((c & 255) << 16) | ((d & 255) << 24));
}

// ---- kernel 1a: numpy-style f32 pairwise partial sums of |w| ----
// leaf = 128 consecutive elems, numpy 8-accumulator pattern. Coalesced:
// 2 lanes/leaf; lane m handles accumulators 4m..4m+3 via float4 loads
// (elem 4m+8k <-> float4 index m+2k). Combine: s_m = (r0+r1)+(r2+r3) per lane,
// leaf = s_0 + s_1 via shfl  == numpy tree ((r0+r1)+(r2+r3))+((r4+r5)+(r6+r7)).
__global__ __launch_bounds__(256) void wsum_leaf(const float* __restrict__ wg,
                                                 const float* __restrict__ wu,
                                                 const float* __restrict__ wd,
                                                 float* __restrict__ part) {
  const float* w = blockIdx.y == 0 ? wg : (blockIdx.y == 1 ? wu : wd);
  int tid = threadIdx.x;
  int wv = tid >> 6, lane = tid & 63;
  int lf = lane >> 1, m = lane & 1;  // 32 leaves per wave-pass, 2 lanes/leaf
  __shared__ float A[256], B[256];
  const float4* w4 = (const float4*)w;
#pragma unroll
  for (int p = 0; p < 2; ++p) {
    int leaf = wv * 64 + p * 32 + lf;                    // block-local leaf id
    size_t b4 = ((size_t)blockIdx.x * 256 + leaf) * 32;  // leaf base (float4)
    float4 v = w4[b4 + m];
    float r0 = fabsf(v.x), r1 = fabsf(v.y), r2 = fabsf(v.z), r3 = fabsf(v.w);
    for (int k = 1; k < 16; ++k) {
      float4 u = w4[b4 + m + 2 * k];
      r0 += fabsf(u.x); r1 += fabsf(u.y); r2 += fabsf(u.z); r3 += fabsf(u.w);
    }
    float s = (r0 + r1) + (r2 + r3);
    float o = __shfl_xor(s, 1, 64);  // partner half
    if (m == 0) A[leaf] = s + o;     // exact numpy order: S0 + S1
  }
  __syncthreads();
  float* src = A; float* dst = B;
  for (int n = 128; n >= 1; n >>= 1) {   // adjacent-pair tree, 8 levels
    if (tid < n) dst[tid] = src[2 * tid] + src[2 * tid + 1];
    __syncthreads();
    float* t = src; src = dst; dst = t;
  }
  if (tid == 0) part[blockIdx.y * NBLK + blockIdx.x] = src[0];
}

// ---- kernel 1b: combine 512 partials per tensor (adjacent-pair tree) ----
__global__ __launch_bounds__(256) void wsum_final(const float* __restrict__ part,
                                                  float* __restrict__ wsc) {
  int t = blockIdx.x, tid = threadIdx.x;
  __shared__ float A[512], B[256];
  A[tid] = part[t * NBLK + tid];
  A[tid + 256] = part[t * NBLK + tid + 256];
  __syncthreads();
  float* src = A; float* dst = B;
  for (int n = 256; n >= 1; n >>= 1) {   // 512 -> 1, 9 levels
    if (tid < n) dst[tid] = src[2 * tid] + src[2 * tid + 1];
    __syncthreads();
    float* tmp = src; src = dst; dst = tmp;
  }
  if (tid == 0) {
    float mean32 = src[0] / (float)WN;       // exact (/2^24)
    float m32 = fmaxf(mean32, 1e-5f);        // np.clip float32
    float s32 = 1.0f / m32;
    wsc[t] = s32;
    wsc[3 + t] = 1.0f / s32;                 // fl32(1/s) dequant value
  }
}

// ---- kernel 2: ternary weight quant, doubled-scale {0,±1,±2};
//      boundary band -> ±1 (i.e. half-weight insurance) ----
__global__ __launch_bounds__(256) void wquant_kernel(const float* __restrict__ wg,
                                                     const float* __restrict__ wu,
                                                     const float* __restrict__ wd,
                                                     const float* __restrict__ wsc,
                                                     int8_t* __restrict__ qg,
                                                     int8_t* __restrict__ qu,
                                                     int8_t* __restrict__ qd) {
  int t = blockIdx.y;
  const float* w = t == 0 ? wg : (t == 1 ? wu : wd);
  int8_t* q = t == 0 ? qg : (t == 1 ? qu : qd);
  float s32 = wsc[t];
  const float4* w4 = (const float4*)w;
  uint32_t* q4 = (uint32_t*)q;
  const int n4 = WN / 4;
  for (int i = blockIdx.x * 256 + threadIdx.x; i < n4; i += gridDim.x * 256) {
    float4 v = w4[i];
    float vv[4] = {v.x, v.y, v.z, v.w};
    int o[4];
#pragma unroll
    for (int j = 0; j < 4; ++j) {
      float pf = fabsf(vv[j]) * s32;               // |fl32(w*s)|
      int q2 = 2 * (int)fminf(rintf(pf), 1.0f);    // 0 or 2 (doubled scale)
      if (fabsf(pf - 0.5f) < BANDP) q2 = 1;        // boundary -> half weight
      o[j] = (vv[j] < 0.0f) ? -q2 : q2;
    }
    q4[i] = (uint32_t)((o[0] & 255) | ((o[1] & 255) << 8) |
                       ((o[2] & 255) << 16) | ((o[3] & 255) << 24));
  }
}

// ---- kernel 3: per-token activation quant of x (float32 decisions) ----
__global__ __launch_bounds__(256) void xquant_kernel(const float* __restrict__ x,
                                                     int8_t* __restrict__ qx,
                                                     double* __restrict__ axd) {
  int row = blockIdx.x, tid = threadIdx.x;
  const float4* xr = (const float4*)(x + (size_t)row * HDIM);
  float4 v0 = xr[tid], v1 = xr[tid + 256];
  float m = fmaxf(fmaxf(fmaxf(fabsf(v0.x), fabsf(v0.y)), fmaxf(fabsf(v0.z), fabsf(v0.w))),
                  fmaxf(fmaxf(fabsf(v1.x), fabsf(v1.y)), fmaxf(fabsf(v1.z), fabsf(v1.w))));
  m = wmax64f(m);
  __shared__ float red[4];
  int wid = tid >> 6, lane = tid & 63;
  if (lane == 0) red[wid] = m;
  __syncthreads();
  float mm = fmaxf(fmaxf(red[0], red[1]), fmaxf(red[2], red[3]));
  float c32 = fmaxf(mm, 1e-5f);
  float s32 = 127.0f / c32;
  if (tid == 0) axd[row] = 1.0 / (double)s32;
  uint32_t* q4 = (uint32_t*)(qx + (size_t)row * HDIM);
  q4[tid] = packq_f(v0, s32);
  q4[tid + 256] = packq_f(v1, s32);
}

// ---- kernel 4: fused GEMM1 (gate+up), 2-phase 8-MFMA-cluster schedule ----
// 512 threads, 8 waves (2M x 4N), tile 128x128, per-wave 64x32.
// 3-buffer LDS (3 x 24KB = 72KB, dynamic), counted vmcnt(3) once per K-iter.
// Phase 0: read a0..a3,bg0,bg1 | gload A,G | bar | lgk | prio 8x g-MFMA | bar
// Phase 1: read bu0,bu1 | gload U | vmcnt(3) | bar | lgk | prio 8x u-MFMA | bar
__global__ __launch_bounds__(512, 4) void gemm1_kernel(const int8_t* __restrict__ qx,
                                                       const int8_t* __restrict__ qg,
                                                       const int8_t* __restrict__ qu,
                                                       const float* __restrict__ wsc,
                                                       const double* __restrict__ axd,
                                                       float* __restrict__ h) {
  extern __shared__ char lds[];
  int tid = threadIdx.x, wid = tid >> 6, lane = tid & 63;
  int l15 = lane & 15, lgp = lane >> 4;
  int wr = wid >> 2, wc = wid & 3;  // 2 x 4 waves
  // L2-aware XCD swizzle: xcd = flat&7 owns n-tiles [8*xcd, 8*xcd+8), all m.
  int flat = blockIdx.y * 64 + blockIdx.x;
  int xcd = flat & 7, local = flat >> 3;       // local in [0,256)
  int mt = local >> 3, nl = local & 7;
  int m0 = mt * 128, n0 = (xcd * 8 + nl) * 128;
  const int8_t* bA = qx + (size_t)m0 * HDIM;
  const int8_t* bG = qg + (size_t)n0 * HDIM;
  const int8_t* bU = qu + (size_t)n0 * HDIM;

  v4i accg[4][2], accu[4][2];
  v4i vzero = {0, 0, 0, 0};
#pragma unroll
  for (int i = 0; i < 4; ++i)
#pragma unroll
    for (int j = 0; j < 2; ++j) { accg[i][j] = vzero; accu[i][j] = vzero; }

  int aoff[4], goff[2], uoff[2];
#pragma unroll
  for (int i = 0; i < 4; ++i)
    aoff[i] = lgp * 2048 + (wr * 64 + i * 16 + l15) * 16;
#pragma unroll
  for (int i = 0; i < 2; ++i) {
    goff[i] = 8192 + lgp * 2048 + (wc * 32 + i * 16 + l15) * 16;
    uoff[i] = goff[i] + 8192;
  }

  int srow = tid & 127, sslab = tid >> 7;
  const size_t rA = (size_t)srow * HDIM;
  int sdst = sslab * 2048 + srow * 16;  // within-buffer staging dest

  const int NT = HDIM / 64;  // 32
  // prologue: stage tiles 0,1 into buffers 0,1
  {
    size_t k0 = (size_t)sslab * 16;
    gload_lds16(bA + rA + k0, lds + sdst);
    gload_lds16(bG + rA + k0, lds + sdst + 8192);
    gload_lds16(bU + rA + k0, lds + sdst + 16384);
    size_t k1 = 64 + (size_t)sslab * 16;
    gload_lds16(bA + rA + k1, lds + 24576 + sdst);
    gload_lds16(bG + rA + k1, lds + 24576 + sdst + 8192);
    gload_lds16(bU + rA + k1, lds + 24576 + sdst + 16384);
  }
  asm volatile("s_waitcnt vmcnt(3)" ::: "memory");  // tile-0 batch landed
  __builtin_amdgcn_s_barrier();
  __builtin_amdgcn_sched_barrier(0);

  int c0 = 0, c1 = 24576, c2 = 49152;  // read buf, next buf, write buf
  for (int t = 0; t < NT; ++t) {
    const bool pf = (t + 2 < NT);
    size_t koff = (size_t)(t + 2) * 64 + sslab * 16;
    // ---------- phase 0: all-g (8 MFMA cluster) ----------
    v4i a0 = *(const v4i*)(lds + c0 + aoff[0]);
    v4i a1 = *(const v4i*)(lds + c0 + aoff[1]);
    v4i a2 = *(const v4i*)(lds + c0 + aoff[2]);
    v4i a3 = *(const v4i*)(lds + c0 + aoff[3]);
    v4i bg0 = *(const v4i*)(lds + c0 + goff[0]);
    v4i bg1 = *(const v4i*)(lds + c0 + goff[1]);
    if (pf) {
      gload_lds16(bA + rA + koff, lds + c2 + sdst);
      gload_lds16(bG + rA + koff, lds + c2 + sdst + 8192);
    }
    __builtin_amdgcn_s_barrier();
    asm volatile("s_waitcnt lgkmcnt(0)" ::: "memory");
    __builtin_amdgcn_sched_barrier(0);
    __builtin_amdgcn_s_setprio(1);
    accg[0][0] = MFMA_I8(a0, bg0, accg[0][0], 0, 0, 0);
    accg[0][1] = MFMA_I8(a0, bg1, accg[0][1], 0, 0, 0);
    accg[1][0] = MFMA_I8(a1, bg0, accg[1][0], 0, 0, 0);
    accg[1][1] = MFMA_I8(a1, bg1, accg[1][1], 0, 0, 0);
    accg[2][0] = MFMA_I8(a2, bg0, accg[2][0], 0, 0, 0);
    accg[2][1] = MFMA_I8(a2, bg1, accg[2][1], 0, 0, 0);
    accg[3][0] = MFMA_I8(a3, bg0, accg[3][0], 0, 0, 0);
    accg[3][1] = MFMA_I8(a3, bg1, accg[3][1], 0, 0, 0);
    __builtin_amdgcn_s_setprio(0);
    __builtin_amdgcn_s_barrier();
    // ---------- phase 1: all-u (8 MFMA cluster); counted vmcnt ----------
    v4i bu0 = *(const v4i*)(lds + c0 + uoff[0]);
    v4i bu1 = *(const v4i*)(lds + c0 + uoff[1]);
    if (pf) gload_lds16(bU + rA + koff, lds + c2 + sdst + 16384);
    if (pf)
      asm volatile("s_waitcnt vmcnt(3)" ::: "memory");  // t+1 landed, t+2 in flight
    else
      asm volatile("s_waitcnt vmcnt(0)" ::: "memory");  // tail drain
    __builtin_amdgcn_s_barrier();
    asm volatile("s_waitcnt lgkmcnt(0)" ::: "memory");
    __builtin_amdgcn_sched_barrier(0);
    __builtin_amdgcn_s_setprio(1);
    accu[0][0] = MFMA_I8(a0, bu0, accu[0][0], 0, 0, 0);
    accu[0][1] = MFMA_I8(a0, bu1, accu[0][1], 0, 0, 0);
    accu[1][0] = MFMA_I8(a1, bu0, accu[1][0], 0, 0, 0);
    accu[1][1] = MFMA_I8(a1, bu1, accu[1][1], 0, 0, 0);
    accu[2][0] = MFMA_I8(a2, bu0, accu[2][0], 0, 0, 0);
    accu[2][1] = MFMA_I8(a2, bu1, accu[2][1], 0, 0, 0);
    accu[3][0] = MFMA_I8(a3, bu0, accu[3][0], 0, 0, 0);
    accu[3][1] = MFMA_I8(a3, bu1, accu[3][1], 0, 0, 0);
    __builtin_amdgcn_s_setprio(0);
    __builtin_amdgcn_s_barrier();
    int tmp = c0; c0 = c1; c1 = c2; c2 = tmp;  // rotate buffers
  }

  double mg = 0.5 * (double)wsc[3 + 0];  // halved: doubled-scale weights
  double mu = 0.5 * (double)wsc[3 + 1];
#pragma unroll
  for (int mi = 0; mi < 4; ++mi) {
#pragma unroll
    for (int rg = 0; rg < 4; ++rg) {
      int grow = m0 + wr * 64 + mi * 16 + lgp * 4 + rg;
      double axr = axd[grow];
      double sg = axr * mg, su = axr * mu;
#pragma unroll
      for (int ni = 0; ni < 2; ++ni) {
        int gcol = n0 + wc * 32 + ni * 16 + l15;
        double g = (double)accg[mi][ni][rg] * sg;
        double u = (double)accu[mi][ni][rg] * su;
        double sig = 1.0 / (1.0 + exp(-g));
        h[(size_t)grow * IDIM + gcol] = (float)((g * sig) * u);
      }
    }
  }
}

// ---- kernel 5: per-row rms-norm + activation quant of h ----
__global__ __launch_bounds__(256) void hquant_kernel(const float* __restrict__ h,
                                                     const float* __restrict__ lnw,
                                                     double* __restrict__ ahd,
                                                     int8_t* __restrict__ qh) {
  int row = blockIdx.x, tid = threadIdx.x;
  const float4* hr = (const float4*)(h + (size_t)row * IDIM);
  const float4* lw4 = (const float4*)lnw;
  float4 hv[8], wv[8];
  double ssq = 0.0;
#pragma unroll
  for (int i = 0; i < 8; ++i) {
    hv[i] = hr[tid + i * 256];
    wv[i] = lw4[tid + i * 256];
    ssq += (double)hv[i].x * hv[i].x + (double)hv[i].y * hv[i].y +
           (double)hv[i].z * hv[i].z + (double)hv[i].w * hv[i].w;
  }
  ssq = wsum64d(ssq);
  __shared__ double redd[4];
  __shared__ double redm[4];
  int wid = tid >> 6, lane = tid & 63;
  if (lane == 0) redd[wid] = ssq;
  __syncthreads();
  double tot = redd[0] + redd[1] + redd[2] + redd[3];
  double rd = 1.0 / sqrt(tot * (1.0 / (double)IDIM) + 1e-6);
  double mx = 0.0;
#pragma unroll
  for (int i = 0; i < 8; ++i) {
    double y0 = (double)wv[i].x * ((double)hv[i].x * rd);
    double y1 = (double)wv[i].y * ((double)hv[i].y * rd);
    double y2 = (double)wv[i].z * ((double)hv[i].z * rd);
    double y3 = (double)wv[i].w * ((double)hv[i].w * rd);
    mx = fmax(mx, fmax(fmax(fabs(y0), fabs(y1)), fmax(fabs(y2), fabs(y3))));
  }
  mx = wmax64d(mx);
  if (lane == 0) redm[wid] = mx;
  __syncthreads();
  double mm = fmax(fmax(redm[0], redm[1]), fmax(redm[2], redm[3]));
  float c32 = fmaxf((float)mm, 1e-5f);
  float s32 = 127.0f / c32;
  double sd = (double)s32;
  if (tid == 0) ahd[row] = 1.0 / (double)s32;
  uint32_t* q4 = (uint32_t*)(qh + (size_t)row * IDIM);
#pragma unroll
  for (int i = 0; i < 8; ++i) {
    double y0 = (double)wv[i].x * ((double)hv[i].x * rd);
    double y1 = (double)wv[i].y * ((double)hv[i].y * rd);
    double y2 = (double)wv[i].z * ((double)hv[i].z * rd);
    double y3 = (double)wv[i].w * ((double)hv[i].w * rd);
    int a = (int)fmin(fmax(rint(y0 * sd), -128.0), 127.0);
    int b = (int)fmin(fmax(rint(y1 * sd), -128.0), 127.0);
    int c = (int)fmin(fmax(rint(y2 * sd), -128.0), 127.0);
    int d = (int)fmin(fmax(rint(y3 * sd), -128.0), 127.0);
    q4[tid + i * 256] = (uint32_t)((a & 255) | ((b & 255) << 8) | ((c & 255) << 16) | ((d & 255) << 24));
  }
}

// ---- kernel 6: GEMM2 (down proj), 2-phase-per-iter schedule (R12) ----
// 512 threads, tile 128x128; 3-buffer dynamic LDS = 48KB; counted vmcnt(2).
__global__ __launch_bounds__(512, 4) void gemm2_kernel(const int8_t* __restrict__ qh,
                                                       const int8_t* __restrict__ qd,
                                                       const float* __restrict__ wsc,
                                                       const double* __restrict__ ahd,
                                                       float* __restrict__ out) {
  extern __shared__ char lds[];
  int tid = threadIdx.x, wid = tid >> 6, lane = tid & 63;
  int l15 = lane & 15, lgp = lane >> 4;
  int wr = wid >> 2, wc = wid & 3;
  int flat = blockIdx.y * 16 + blockIdx.x;     // [0,512)
  int xcd = flat & 7, local = flat >> 3;       // local in [0,64)
  int mt = xcd * 4 + (local >> 4), nt = local & 15;
  int m0 = mt * 128, n0 = nt * 128;
  const int8_t* bA = qh + (size_t)m0 * IDIM;
  const int8_t* bB = qd + (size_t)n0 * IDIM;

  v4i acc[4][2];
  v4i vzero = {0, 0, 0, 0};
#pragma unroll
  for (int i = 0; i < 4; ++i)
#pragma unroll
    for (int j = 0; j < 2; ++j) acc[i][j] = vzero;

  int aoff[4], boff[2];
#pragma unroll
  for (int i = 0; i < 4; ++i)
    aoff[i] = lgp * 2048 + (wr * 64 + i * 16 + l15) * 16;
#pragma unroll
  for (int i = 0; i < 2; ++i)
    boff[i] = 8192 + lgp * 2048 + (wc * 32 + i * 16 + l15) * 16;

  int srow = tid & 127, sslab = tid >> 7;
  const size_t rA = (size_t)srow * IDIM;
  int sdst = sslab * 2048 + srow * 16;

  const int NT = IDIM / 64;  // 128
  {
    size_t k0 = (size_t)sslab * 16;
    gload_lds16(bA + rA + k0, lds + sdst);
    gload_lds16(bB + rA + k0, lds + sdst + 8192);
    size_t k1 = 64 + (size_t)sslab * 16;
    gload_lds16(bA + rA + k1, lds + 16384 + sdst);
    gload_lds16(bB + rA + k1, lds + 16384 + sdst + 8192);
  }
  asm volatile("s_waitcnt vmcnt(2)" ::: "memory");
  __builtin_amdgcn_s_barrier();
  __builtin_amdgcn_sched_barrier(0);

  int c0 = 0, c1 = 16384, c2 = 32768;
  for (int t = 0; t < NT; ++t) {
    const bool pf = (t + 2 < NT);
    size_t koff = (size_t)(t + 2) * 64 + sslab * 16;
    // ---------- phase 0: mi{0,1} ----------
    v4i a0 = *(const v4i*)(lds + c0 + aoff[0]);
    v4i a1 = *(const v4i*)(lds + c0 + aoff[1]);
    v4i b0 = *(const v4i*)(lds + c0 + boff[0]);
    v4i b1 = *(const v4i*)(lds + c0 + boff[1]);
    if (pf) gload_lds16(bA + rA + koff, lds + c2 + sdst);
    __builtin_amdgcn_s_barrier();
    asm volatile("s_waitcnt lgkmcnt(0)" ::: "memory");
    __builtin_amdgcn_sched_barrier(0);
    __builtin_amdgcn_s_setprio(1);
    acc[0][0] = MFMA_I8(a0, b0, acc[0][0], 0, 0, 0);
    acc[0][1] = MFMA_I8(a0, b1, acc[0][1], 0, 0, 0);
    acc[1][0] = MFMA_I8(a1, b0, acc[1][0], 0, 0, 0);
    acc[1][1] = MFMA_I8(a1, b1, acc[1][1], 0, 0, 0);
    __builtin_amdgcn_s_setprio(0);
    __builtin_amdgcn_s_barrier();
    // ---------- phase 1: mi{2,3}; counted vmcnt ----------
    v4i a2 = *(const v4i*)(lds + c0 + aoff[2]);
    v4i a3 = *(const v4i*)(lds + c0 + aoff[3]);
    if (pf) gload_lds16(bB + rA + koff, lds + c2 + sdst + 8192);
    if (pf)
      asm volatile("s_waitcnt vmcnt(2)" ::: "memory");
    else
      asm volatile("s_waitcnt vmcnt(0)" ::: "memory");
    __builtin_amdgcn_s_barrier();
    asm volatile("s_waitcnt lgkmcnt(0)" ::: "memory");
    __builtin_amdgcn_sched_barrier(0);
    __builtin_amdgcn_s_setprio(1);
    acc[2][0] = MFMA_I8(a2, b0, acc[2][0], 0, 0, 0);
    acc[2][1] = MFMA_I8(a2, b1, acc[2][1], 0, 0, 0);
    acc[3][0] = MFMA_I8(a3, b0, acc[3][0], 0, 0, 0);
    acc[3][1] = MFMA_I8(a3, b1, acc[3][1], 0, 0, 0);
    __builtin_amdgcn_s_setprio(0);
    __builtin_amdgcn_s_barrier();
    int tmp = c0; c0 = c1; c1 = c2; c2 = tmp;
  }

  double md = 0.5 * (double)wsc[3 + 2];  // halved: doubled-scale weights
#pragma unroll
  for (int mi = 0; mi < 4; ++mi) {
#pragma unroll
    for (int rg = 0; rg < 4; ++rg) {
      int grow = m0 + wr * 64 + mi * 16 + lgp * 4 + rg;
      double sc = ahd[grow] * md;
#pragma unroll
      for (int ni = 0; ni < 2; ++ni) {
        int gcol = n0 + wc * 32 + ni * 16 + l15;
        out[(size_t)grow * HDIM + gcol] = (float)((double)acc[mi][ni][rg] * sc);
      }
    }
  }
}

extern "C" void kernel_launch(void* const* d_in, const int* in_sizes, int n_in,
                              void* d_out, int out_size, void* d_ws, size_t ws_size,
                              hipStream_t stream) {
  const float* x   = (const float*)d_in[0];
  const float* wg  = (const float*)d_in[1];
  const float* wu  = (const float*)d_in[2];
  const float* wd  = (const float*)d_in[3];
  const float* lnw = (const float*)d_in[4];
  float* out = (float*)d_out;
  char* ws = (char*)d_ws;

  size_t off = 0;
  auto alloc = [&](size_t b) { size_t o = off; off += (b + 255) & ~(size_t)255; return o; };
  size_t o_wsc  = alloc(8 * 4);                 // s32[3], fl32(1/s)[3]
  size_t o_part = alloc(3 * NBLK * 4);
  size_t o_axd  = alloc((size_t)TOKENS * 8);
  size_t o_ahd  = alloc((size_t)TOKENS * 8);
  size_t o_qx   = alloc((size_t)TOKENS * HDIM);
  size_t o_qg   = alloc((size_t)IDIM * HDIM);   // qh later overlays qg
  size_t o_qu   = alloc((size_t)IDIM * HDIM);
  size_t o_qd   = alloc((size_t)HDIM * IDIM);
  size_t o_h    = alloc((size_t)TOKENS * IDIM * 4);
  (void)ws_size; (void)in_sizes; (void)n_in; (void)out_size; (void)o_qu;

  float* wsc  = (float*)(ws + o_wsc);
  float* part = (float*)(ws + o_part);
  double* axd = (double*)(ws + o_axd);
  double* ahd = (double*)(ws + o_ahd);
  int8_t* qx  = (int8_t*)(ws + o_qx);
  int8_t* qg  = (int8_t*)(ws + o_qg);
  int8_t* qu  = (int8_t*)(ws + o_qu);
  int8_t* qd  = (int8_t*)(ws + o_qd);
  int8_t* qh  = (int8_t*)(ws + o_qg);  // overlay: qg/qu dead after gemm1
  float* h    = (float*)(ws + o_h);

  wsum_leaf<<<dim3(NBLK, 3), 256, 0, stream>>>(wg, wu, wd, part);
  wsum_final<<<3, 256, 0, stream>>>(part, wsc);
  wquant_kernel<<<dim3(1024, 3), 256, 0, stream>>>(wg, wu, wd, wsc, qg, qu, qd);
  xquant_kernel<<<TOKENS, 256, 0, stream>>>(x, qx, axd);
  gemm1_kernel<<<dim3(IDIM / 128, TOKENS / 128), 512, 3 * 24576, stream>>>(qx, qg, qu, wsc, axd, h);
  hquant_kernel<<<TOKENS, 256, 0, stream>>>(h, lnw, ahd, qh);
  gemm2_kernel<<<dim3(HDIM / 128, TOKENS / 128), 512, 3 * 16384, stream>>>(qh, qd, wsc, ahd, out);
}

// Round 15
// 461.057 us; speedup vs baseline: 1.1252x; 1.0870x over previous
//
#include <hip/hip_runtime.h>
#include <stdint.h>

typedef int v4i __attribute__((ext_vector_type(4)));

#define TOKENS 4096   // B*S
#define HDIM   2048   // H
#define IDIM   8192   // I
#define WN     16777216  // elements per weight tensor (I*H == H*I) = 2^24
#define NBLK   512       // partial blocks per tensor (each = 256 leaves of 128)
#define BANDP  5e-7f     // half-split insurance band around the 0.5 boundary

#define MFMA_I8 __builtin_amdgcn_mfma_i32_16x16x64_i8

// ---- async global->LDS, 16B per lane (dest = uniform base + lane*16) ----
static __device__ __forceinline__ void gload_lds16(const void* g, void* l) {
  __builtin_amdgcn_global_load_lds(
      (const __attribute__((address_space(1))) void*)(unsigned long long)(uintptr_t)g,
      (__attribute__((address_space(3))) void*)(unsigned)(uintptr_t)l,
      16, 0, 0);
}

static __device__ __forceinline__ double wsum64d(double v) {
#pragma unroll
  for (int m = 32; m; m >>= 1) v += __shfl_xor(v, m, 64);
  return v;
}
static __device__ __forceinline__ double wmax64d(double v) {
#pragma unroll
  for (int m = 32; m; m >>= 1) v = fmax(v, __shfl_xor(v, m, 64));
  return v;
}
static __device__ __forceinline__ float wmax64f(float v) {
#pragma unroll
  for (int m = 32; m; m >>= 1) v = fmaxf(v, __shfl_xor(v, m, 64));
  return v;
}

// f32 quant decision (single f32 product rounding, like jax/np float32)
static __device__ __forceinline__ int q8f(float v, float s, float lo, float hi) {
  float p = v * s;
  return (int)fminf(fmaxf(rintf(p), lo), hi);
}
static __device__ __forceinline__ uint32_t packq_f(float4 v, float s) {
  int a = q8f(v.x, s, -128.f, 127.f);
  int b = q8f(v.y, s, -128.f, 127.f);
  int c = q8f(v.z, s, -128.f, 127.f);
  int d = q8f(v.w, s, -128.f, 127.f);
  return (uint32_t)((a & 255) | ((b & 255) << 8) | ((c & 255) << 16) | ((d & 255) << 24));
}

// ---- kernel 1a: numpy-style f32 pairwise partial sums of |w| (coalesced) ----
__global__ __launch_bounds__(256) void wsum_leaf(const float* __restrict__ wg,
                                                 const float* __restrict__ wu,
                                                 const float* __restrict__ wd,
                                                 float* __restrict__ part) {
  const float* w = blockIdx.y == 0 ? wg : (blockIdx.y == 1 ? wu : wd);
  int tid = threadIdx.x;
  int wv = tid >> 6, lane = tid & 63;
  int lf = lane >> 1, m = lane & 1;  // 32 leaves per wave-pass, 2 lanes/leaf
  __shared__ float A[256], B[256];
  const float4* w4 = (const float4*)w;
#pragma unroll
  for (int p = 0; p < 2; ++p) {
    int leaf = wv * 64 + p * 32 + lf;                    // block-local leaf id
    size_t b4 = ((size_t)blockIdx.x * 256 + leaf) * 32;  // leaf base (float4)
    float4 v = w4[b4 + m];
    float r0 = fabsf(v.x), r1 = fabsf(v.y), r2 = fabsf(v.z), r3 = fabsf(v.w);
    for (int k = 1; k < 16; ++k) {
      float4 u = w4[b4 + m + 2 * k];
      r0 += fabsf(u.x); r1 += fabsf(u.y); r2 += fabsf(u.z); r3 += fabsf(u.w);
    }
    float s = (r0 + r1) + (r2 + r3);
    float o = __shfl_xor(s, 1, 64);  // partner half
    if (m == 0) A[leaf] = s + o;     // exact numpy order: S0 + S1
  }
  __syncthreads();
  float* src = A; float* dst = B;
  for (int n = 128; n >= 1; n >>= 1) {   // adjacent-pair tree, 8 levels
    if (tid < n) dst[tid] = src[2 * tid] + src[2 * tid + 1];
    __syncthreads();
    float* t = src; src = dst; dst = t;
  }
  if (tid == 0) part[blockIdx.y * NBLK + blockIdx.x] = src[0];
}

// ---- kernel 1b: combine 512 partials per tensor (adjacent-pair tree) ----
__global__ __launch_bounds__(256) void wsum_final(const float* __restrict__ part,
                                                  float* __restrict__ wsc) {
  int t = blockIdx.x, tid = threadIdx.x;
  __shared__ float A[512], B[256];
  A[tid] = part[t * NBLK + tid];
  A[tid + 256] = part[t * NBLK + tid + 256];
  __syncthreads();
  float* src = A; float* dst = B;
  for (int n = 256; n >= 1; n >>= 1) {   // 512 -> 1, 9 levels
    if (tid < n) dst[tid] = src[2 * tid] + src[2 * tid + 1];
    __syncthreads();
    float* tmp = src; src = dst; dst = tmp;
  }
  if (tid == 0) {
    float mean32 = src[0] / (float)WN;       // exact (/2^24)
    float m32 = fmaxf(mean32, 1e-5f);        // np.clip float32
    float s32 = 1.0f / m32;
    wsc[t] = s32;
    wsc[3 + t] = 1.0f / s32;                 // fl32(1/s) dequant value
  }
}

// ---- kernel 2: ternary weight quant, doubled-scale {0,±1,±2};
//      boundary band -> ±1 (i.e. half-weight insurance) ----
__global__ __launch_bounds__(256) void wquant_kernel(const float* __restrict__ wg,
                                                     const float* __restrict__ wu,
                                                     const float* __restrict__ wd,
                                                     const float* __restrict__ wsc,
                                                     int8_t* __restrict__ qg,
                                                     int8_t* __restrict__ qu,
                                                     int8_t* __restrict__ qd) {
  int t = blockIdx.y;
  const float* w = t == 0 ? wg : (t == 1 ? wu : wd);
  int8_t* q = t == 0 ? qg : (t == 1 ? qu : qd);
  float s32 = wsc[t];
  const float4* w4 = (const float4*)w;
  uint32_t* q4 = (uint32_t*)q;
  const int n4 = WN / 4;
  for (int i = blockIdx.x * 256 + threadIdx.x; i < n4; i += gridDim.x * 256) {
    float4 v = w4[i];
    float vv[4] = {v.x, v.y, v.z, v.w};
    int o[4];
#pragma unroll
    for (int j = 0; j < 4; ++j) {
      float pf = fabsf(vv[j]) * s32;               // |fl32(w*s)|
      int q2 = 2 * (int)fminf(rintf(pf), 1.0f);    // 0 or 2 (doubled scale)
      if (fabsf(pf - 0.5f) < BANDP) q2 = 1;        // boundary -> half weight
      o[j] = (vv[j] < 0.0f) ? -q2 : q2;
    }
    q4[i] = (uint32_t)((o[0] & 255) | ((o[1] & 255) << 8) |
                       ((o[2] & 255) << 16) | ((o[3] & 255) << 24));
  }
}

// ---- kernel 3: per-token activation quant of x (float32 decisions) ----
__global__ __launch_bounds__(256) void xquant_kernel(const float* __restrict__ x,
                                                     int8_t* __restrict__ qx,
                                                     double* __restrict__ axd) {
  int row = blockIdx.x, tid = threadIdx.x;
  const float4* xr = (const float4*)(x + (size_t)row * HDIM);
  float4 v0 = xr[tid], v1 = xr[tid + 256];
  float m = fmaxf(fmaxf(fmaxf(fabsf(v0.x), fabsf(v0.y)), fmaxf(fabsf(v0.z), fabsf(v0.w))),
                  fmaxf(fmaxf(fabsf(v1.x), fabsf(v1.y)), fmaxf(fabsf(v1.z), fabsf(v1.w))));
  m = wmax64f(m);
  __shared__ float red[4];
  int wid = tid >> 6, lane = tid & 63;
  if (lane == 0) red[wid] = m;
  __syncthreads();
  float mm = fmaxf(fmaxf(red[0], red[1]), fmaxf(red[2], red[3]));
  float c32 = fmaxf(mm, 1e-5f);
  float s32 = 127.0f / c32;
  if (tid == 0) axd[row] = 1.0 / (double)s32;
  uint32_t* q4 = (uint32_t*)(qx + (size_t)row * HDIM);
  q4[tid] = packq_f(v0, s32);
  q4[tid + 256] = packq_f(v1, s32);
}

// ---- kernel 4: fused GEMM1 (gate+up), 256x128 tile, 4-phase 8-MFMA clusters ----
// 512 threads, 8 waves (2M x 4N), per-wave 128x32 per tensor.
// acc = accg[8][2]+accu[8][2] = 128 VGPR; launch_bounds (512,2) -> 256 cap.
// LDS/buffer 32KB: A[4 slab][256 row][16B] @0, G[4][128][16] @16384, U @24576.
// 3 buffers = 96KB static -> 1 block/CU (8 waves, 2/SIMD intra-phase overlap).
// Per iter: 4 phases {ds_reads | gloads(t+2) | bar | lgkmcnt0+SB | prio 8xMFMA | bar},
// counted vmcnt(4) only in phase 3 (4 staging loads/iter stay in flight).
__global__ __launch_bounds__(512, 2) void gemm1_kernel(const int8_t* __restrict__ qx,
                                                       const int8_t* __restrict__ qg,
                                                       const int8_t* __restrict__ qu,
                                                       const float* __restrict__ wsc,
                                                       const double* __restrict__ axd,
                                                       float* __restrict__ h) {
  __shared__ char lds[98304];
  int tid = threadIdx.x, wid = tid >> 6, lane = tid & 63;
  int l15 = lane & 15, lgp = lane >> 4;
  int wr = wid >> 2, wc = wid & 3;  // 2M x 4N waves
  // XCD swizzle: grid 64n x 16m = 1024 blocks; xcd owns 8-n-tile strip (4MB L2).
  int flat = blockIdx.y * 64 + blockIdx.x;
  int xcd = flat & 7, local = flat >> 3;       // local in [0,128)
  int mt = local >> 3, nl = local & 7;
  int m0 = mt * 256, n0 = (xcd * 8 + nl) * 128;
  const int8_t* bA = qx + (size_t)m0 * HDIM;
  const int8_t* bG = qg + (size_t)n0 * HDIM;
  const int8_t* bU = qu + (size_t)n0 * HDIM;

  v4i accg[8][2], accu[8][2];
  v4i vzero = {0, 0, 0, 0};
#pragma unroll
  for (int i = 0; i < 8; ++i)
#pragma unroll
    for (int j = 0; j < 2; ++j) { accg[i][j] = vzero; accu[i][j] = vzero; }

  int aoff[8], goff[2], uoff[2];
#pragma unroll
  for (int i = 0; i < 8; ++i)
    aoff[i] = lgp * 4096 + (wr * 128 + i * 16 + l15) * 16;
#pragma unroll
  for (int i = 0; i < 2; ++i) {
    goff[i] = 16384 + lgp * 2048 + (wc * 32 + i * 16 + l15) * 16;
    uoff[i] = goff[i] + 8192;
  }

  // staging maps (all wave-uniform base + lane*16):
  // A: 1024 (slab,row) pairs; thread does row rA8=tid&255, slabs sA and sA+2.
  int rA8 = tid & 255, sA = tid >> 8;
  int sdA0 = sA * 4096 + rA8 * 16;             // slab sA
  int sdA1 = sdA0 + 8192;                      // slab sA+2
  const size_t gA = (size_t)rA8 * HDIM;
  // G/U: 512 pairs; thread does row rG=tid&127, slab sG.
  int rG = tid & 127, sG = tid >> 7;
  int sdG = 16384 + sG * 2048 + rG * 16;
  const size_t gG = (size_t)rG * HDIM;

  const int NT = HDIM / 64;  // 32
  // prologue: stage tiles 0,1 into buffers 0,1 (4 loads each)
#pragma unroll
  for (int t0 = 0; t0 < 2; ++t0) {
    int cb = t0 * 32768;
    size_t kt = (size_t)t0 * 64;
    gload_lds16(bA + gA + kt + sA * 16,        lds + cb + sdA0);
    gload_lds16(bA + gA + kt + 32 + sA * 16,   lds + cb + sdA1);
    gload_lds16(bG + gG + kt + sG * 16,        lds + cb + sdG);
    gload_lds16(bU + gG + kt + sG * 16,        lds + cb + sdG + 8192);
  }
  asm volatile("s_waitcnt vmcnt(4)" ::: "memory");  // tile-0 batch landed
  __builtin_amdgcn_s_barrier();
  __builtin_amdgcn_sched_barrier(0);

  int c0 = 0, c1 = 32768, c2 = 65536;
  for (int t = 0; t < NT; ++t) {
    const bool pf = (t + 2 < NT);
    size_t kt2 = (size_t)(t + 2) * 64;
    // ---------- phase 0: g x mi0-3 ----------
    v4i a0 = *(const v4i*)(lds + c0 + aoff[0]);
    v4i a1 = *(const v4i*)(lds + c0 + aoff[1]);
    v4i a2 = *(const v4i*)(lds + c0 + aoff[2]);
    v4i a3 = *(const v4i*)(lds + c0 + aoff[3]);
    v4i bg0 = *(const v4i*)(lds + c0 + goff[0]);
    v4i bg1 = *(const v4i*)(lds + c0 + goff[1]);
    if (pf) {
      gload_lds16(bA + gA + kt2 + sA * 16,      lds + c2 + sdA0);
      gload_lds16(bA + gA + kt2 + 32 + sA * 16, lds + c2 + sdA1);
    }
    __builtin_amdgcn_s_barrier();
    asm volatile("s_waitcnt lgkmcnt(0)" ::: "memory");
    __builtin_amdgcn_sched_barrier(0);
    __builtin_amdgcn_s_setprio(1);
    accg[0][0] = MFMA_I8(a0, bg0, accg[0][0], 0, 0, 0);
    accg[0][1] = MFMA_I8(a0, bg1, accg[0][1], 0, 0, 0);
    accg[1][0] = MFMA_I8(a1, bg0, accg[1][0], 0, 0, 0);
    accg[1][1] = MFMA_I8(a1, bg1, accg[1][1], 0, 0, 0);
    accg[2][0] = MFMA_I8(a2, bg0, accg[2][0], 0, 0, 0);
    accg[2][1] = MFMA_I8(a2, bg1, accg[2][1], 0, 0, 0);
    accg[3][0] = MFMA_I8(a3, bg0, accg[3][0], 0, 0, 0);
    accg[3][1] = MFMA_I8(a3, bg1, accg[3][1], 0, 0, 0);
    __builtin_amdgcn_s_setprio(0);
    __builtin_amdgcn_s_barrier();
    // ---------- phase 1: g x mi4-7 ----------
    v4i a4 = *(const v4i*)(lds + c0 + aoff[4]);
    v4i a5 = *(const v4i*)(lds + c0 + aoff[5]);
    v4i a6 = *(const v4i*)(lds + c0 + aoff[6]);
    v4i a7 = *(const v4i*)(lds + c0 + aoff[7]);
    if (pf) gload_lds16(bG + gG + kt2 + sG * 16, lds + c2 + sdG);
    __builtin_amdgcn_s_barrier();
    asm volatile("s_waitcnt lgkmcnt(0)" ::: "memory");
    __builtin_amdgcn_sched_barrier(0);
    __builtin_amdgcn_s_setprio(1);
    accg[4][0] = MFMA_I8(a4, bg0, accg[4][0], 0, 0, 0);
    accg[4][1] = MFMA_I8(a4, bg1, accg[4][1], 0, 0, 0);
    accg[5][0] = MFMA_I8(a5, bg0, accg[5][0], 0, 0, 0);
    accg[5][1] = MFMA_I8(a5, bg1, accg[5][1], 0, 0, 0);
    accg[6][0] = MFMA_I8(a6, bg0, accg[6][0], 0, 0, 0);
    accg[6][1] = MFMA_I8(a6, bg1, accg[6][1], 0, 0, 0);
    accg[7][0] = MFMA_I8(a7, bg0, accg[7][0], 0, 0, 0);
    accg[7][1] = MFMA_I8(a7, bg1, accg[7][1], 0, 0, 0);
    __builtin_amdgcn_s_setprio(0);
    __builtin_amdgcn_s_barrier();
    // ---------- phase 2: u x mi0-3 ----------
    v4i bu0 = *(const v4i*)(lds + c0 + uoff[0]);
    v4i bu1 = *(const v4i*)(lds + c0 + uoff[1]);
    if (pf) gload_lds16(bU + gG + kt2 + sG * 16, lds + c2 + sdG + 8192);
    __builtin_amdgcn_s_barrier();
    asm volatile("s_waitcnt lgkmcnt(0)" ::: "memory");
    __builtin_amdgcn_sched_barrier(0);
    __builtin_amdgcn_s_setprio(1);
    accu[0][0] = MFMA_I8(a0, bu0, accu[0][0], 0, 0, 0);
    accu[0][1] = MFMA_I8(a0, bu1, accu[0][1], 0, 0, 0);
    accu[1][0] = MFMA_I8(a1, bu0, accu[1][0], 0, 0, 0);
    accu[1][1] = MFMA_I8(a1, bu1, accu[1][1], 0, 0, 0);
    accu[2][0] = MFMA_I8(a2, bu0, accu[2][0], 0, 0, 0);
    accu[2][1] = MFMA_I8(a2, bu1, accu[2][1], 0, 0, 0);
    accu[3][0] = MFMA_I8(a3, bu0, accu[3][0], 0, 0, 0);
    accu[3][1] = MFMA_I8(a3, bu1, accu[3][1], 0, 0, 0);
    __builtin_amdgcn_s_setprio(0);
    __builtin_amdgcn_s_barrier();
    // ---------- phase 3: u x mi4-7; rotation fence ----------
    if (pf)
      asm volatile("s_waitcnt vmcnt(4)" ::: "memory");  // t+1 landed, t+2 in flight
    else
      asm volatile("s_waitcnt vmcnt(0)" ::: "memory");  // tail drain
    __builtin_amdgcn_s_barrier();
    __builtin_amdgcn_sched_barrier(0);
    __builtin_amdgcn_s_setprio(1);
    accu[4][0] = MFMA_I8(a4, bu0, accu[4][0], 0, 0, 0);
    accu[4][1] = MFMA_I8(a4, bu1, accu[4][1], 0, 0, 0);
    accu[5][0] = MFMA_I8(a5, bu0, accu[5][0], 0, 0, 0);
    accu[5][1] = MFMA_I8(a5, bu1, accu[5][1], 0, 0, 0);
    accu[6][0] = MFMA_I8(a6, bu0, accu[6][0], 0, 0, 0);
    accu[6][1] = MFMA_I8(a6, bu1, accu[6][1], 0, 0, 0);
    accu[7][0] = MFMA_I8(a7, bu0, accu[7][0], 0, 0, 0);
    accu[7][1] = MFMA_I8(a7, bu1, accu[7][1], 0, 0, 0);
    __builtin_amdgcn_s_setprio(0);
    __builtin_amdgcn_s_barrier();
    int tmp = c0; c0 = c1; c1 = c2; c2 = tmp;  // rotate buffers
  }

  double mg = 0.5 * (double)wsc[3 + 0];  // halved: doubled-scale weights
  double mu = 0.5 * (double)wsc[3 + 1];
#pragma unroll
  for (int mi = 0; mi < 8; ++mi) {
#pragma unroll
    for (int rg = 0; rg < 4; ++rg) {
      int grow = m0 + wr * 128 + mi * 16 + lgp * 4 + rg;
      double axr = axd[grow];
      double sg = axr * mg, su = axr * mu;
#pragma unroll
      for (int ni = 0; ni < 2; ++ni) {
        int gcol = n0 + wc * 32 + ni * 16 + l15;
        double g = (double)accg[mi][ni][rg] * sg;
        double u = (double)accu[mi][ni][rg] * su;
        double sig = 1.0 / (1.0 + exp(-g));
        h[(size_t)grow * IDIM + gcol] = (float)((g * sig) * u);
      }
    }
  }
}

// ---- kernel 5: per-row rms-norm + activation quant of h ----
__global__ __launch_bounds__(256) void hquant_kernel(const float* __restrict__ h,
                                                     const float* __restrict__ lnw,
                                                     double* __restrict__ ahd,
                                                     int8_t* __restrict__ qh) {
  int row = blockIdx.x, tid = threadIdx.x;
  const float4* hr = (const float4*)(h + (size_t)row * IDIM);
  const float4* lw4 = (const float4*)lnw;
  float4 hv[8], wv[8];
  double ssq = 0.0;
#pragma unroll
  for (int i = 0; i < 8; ++i) {
    hv[i] = hr[tid + i * 256];
    wv[i] = lw4[tid + i * 256];
    ssq += (double)hv[i].x * hv[i].x + (double)hv[i].y * hv[i].y +
           (double)hv[i].z * hv[i].z + (double)hv[i].w * hv[i].w;
  }
  ssq = wsum64d(ssq);
  __shared__ double redd[4];
  __shared__ double redm[4];
  int wid = tid >> 6, lane = tid & 63;
  if (lane == 0) redd[wid] = ssq;
  __syncthreads();
  double tot = redd[0] + redd[1] + redd[2] + redd[3];
  double rd = 1.0 / sqrt(tot * (1.0 / (double)IDIM) + 1e-6);
  double mx = 0.0;
#pragma unroll
  for (int i = 0; i < 8; ++i) {
    double y0 = (double)wv[i].x * ((double)hv[i].x * rd);
    double y1 = (double)wv[i].y * ((double)hv[i].y * rd);
    double y2 = (double)wv[i].z * ((double)hv[i].z * rd);
    double y3 = (double)wv[i].w * ((double)hv[i].w * rd);
    mx = fmax(mx, fmax(fmax(fabs(y0), fabs(y1)), fmax(fabs(y2), fabs(y3))));
  }
  mx = wmax64d(mx);
  if (lane == 0) redm[wid] = mx;
  __syncthreads();
  double mm = fmax(fmax(redm[0], redm[1]), fmax(redm[2], redm[3]));
  float c32 = fmaxf((float)mm, 1e-5f);
  float s32 = 127.0f / c32;
  double sd = (double)s32;
  if (tid == 0) ahd[row] = 1.0 / (double)s32;
  uint32_t* q4 = (uint32_t*)(qh + (size_t)row * IDIM);
#pragma unroll
  for (int i = 0; i < 8; ++i) {
    double y0 = (double)wv[i].x * ((double)hv[i].x * rd);
    double y1 = (double)wv[i].y * ((double)hv[i].y * rd);
    double y2 = (double)wv[i].z * ((double)hv[i].z * rd);
    double y3 = (double)wv[i].w * ((double)hv[i].w * rd);
    int a = (int)fmin(fmax(rint(y0 * sd), -128.0), 127.0);
    int b = (int)fmin(fmax(rint(y1 * sd), -128.0), 127.0);
    int c = (int)fmin(fmax(rint(y2 * sd), -128.0), 127.0);
    int d = (int)fmin(fmax(rint(y3 * sd), -128.0), 127.0);
    q4[tid + i * 256] = (uint32_t)((a & 255) | ((b & 255) << 8) | ((c & 255) << 16) | ((d & 255) << 24));
  }
}

// ---- kernel 6: GEMM2 (down proj), 2-phase-per-iter schedule (R12 best) ----
// 512 threads, tile 128x128; 3-buffer dynamic LDS = 48KB; counted vmcnt(2).
__global__ __launch_bounds__(512, 4) void gemm2_kernel(const int8_t* __restrict__ qh,
                                                       const int8_t* __restrict__ qd,
                                                       const float* __restrict__ wsc,
                                                       const double* __restrict__ ahd,
                                                       float* __restrict__ out) {
  extern __shared__ char lds[];
  int tid = threadIdx.x, wid = tid >> 6, lane = tid & 63;
  int l15 = lane & 15, lgp = lane >> 4;
  int wr = wid >> 2, wc = wid & 3;
  int flat = blockIdx.y * 16 + blockIdx.x;     // [0,512)
  int xcd = flat & 7, local = flat >> 3;       // local in [0,64)
  int mt = xcd * 4 + (local >> 4), nt = local & 15;
  int m0 = mt * 128, n0 = nt * 128;
  const int8_t* bA = qh + (size_t)m0 * IDIM;
  const int8_t* bB = qd + (size_t)n0 * IDIM;

  v4i acc[4][2];
  v4i vzero = {0, 0, 0, 0};
#pragma unroll
  for (int i = 0; i < 4; ++i)
#pragma unroll
    for (int j = 0; j < 2; ++j) acc[i][j] = vzero;

  int aoff[4], boff[2];
#pragma unroll
  for (int i = 0; i < 4; ++i)
    aoff[i] = lgp * 2048 + (wr * 64 + i * 16 + l15) * 16;
#pragma unroll
  for (int i = 0; i < 2; ++i)
    boff[i] = 8192 + lgp * 2048 + (wc * 32 + i * 16 + l15) * 16;

  int srow = tid & 127, sslab = tid >> 7;
  const size_t rA = (size_t)srow * IDIM;
  int sdst = sslab * 2048 + srow * 16;

  const int NT = IDIM / 64;  // 128
  {
    size_t k0 = (size_t)sslab * 16;
    gload_lds16(bA + rA + k0, lds + sdst);
    gload_lds16(bB + rA + k0, lds + sdst + 8192);
    size_t k1 = 64 + (size_t)sslab * 16;
    gload_lds16(bA + rA + k1, lds + 16384 + sdst);
    gload_lds16(bB + rA + k1, lds + 16384 + sdst + 8192);
  }
  asm volatile("s_waitcnt vmcnt(2)" ::: "memory");
  __builtin_amdgcn_s_barrier();
  __builtin_amdgcn_sched_barrier(0);

  int c0 = 0, c1 = 16384, c2 = 32768;
  for (int t = 0; t < NT; ++t) {
    const bool pf = (t + 2 < NT);
    size_t koff = (size_t)(t + 2) * 64 + sslab * 16;
    // ---------- phase 0: mi{0,1} ----------
    v4i a0 = *(const v4i*)(lds + c0 + aoff[0]);
    v4i a1 = *(const v4i*)(lds + c0 + aoff[1]);
    v4i b0 = *(const v4i*)(lds + c0 + boff[0]);
    v4i b1 = *(const v4i*)(lds + c0 + boff[1]);
    if (pf) gload_lds16(bA + rA + koff, lds + c2 + sdst);
    __builtin_amdgcn_s_barrier();
    asm volatile("s_waitcnt lgkmcnt(0)" ::: "memory");
    __builtin_amdgcn_sched_barrier(0);
    __builtin_amdgcn_s_setprio(1);
    acc[0][0] = MFMA_I8(a0, b0, acc[0][0], 0, 0, 0);
    acc[0][1] = MFMA_I8(a0, b1, acc[0][1], 0, 0, 0);
    acc[1][0] = MFMA_I8(a1, b0, acc[1][0], 0, 0, 0);
    acc[1][1] = MFMA_I8(a1, b1, acc[1][1], 0, 0, 0);
    __builtin_amdgcn_s_setprio(0);
    __builtin_amdgcn_s_barrier();
    // ---------- phase 1: mi{2,3}; counted vmcnt ----------
    v4i a2 = *(const v4i*)(lds + c0 + aoff[2]);
    v4i a3 = *(const v4i*)(lds + c0 + aoff[3]);
    if (pf) gload_lds16(bB + rA + koff, lds + c2 + sdst + 8192);
    if (pf)
      asm volatile("s_waitcnt vmcnt(2)" ::: "memory");
    else
      asm volatile("s_waitcnt vmcnt(0)" ::: "memory");
    __builtin_amdgcn_s_barrier();
    asm volatile("s_waitcnt lgkmcnt(0)" ::: "memory");
    __builtin_amdgcn_sched_barrier(0);
    __builtin_amdgcn_s_setprio(1);
    acc[2][0] = MFMA_I8(a2, b0, acc[2][0], 0, 0, 0);
    acc[2][1] = MFMA_I8(a2, b1, acc[2][1], 0, 0, 0);
    acc[3][0] = MFMA_I8(a3, b0, acc[3][0], 0, 0, 0);
    acc[3][1] = MFMA_I8(a3, b1, acc[3][1], 0, 0, 0);
    __builtin_amdgcn_s_setprio(0);
    __builtin_amdgcn_s_barrier();
    int tmp = c0; c0 = c1; c1 = c2; c2 = tmp;
  }

  double md = 0.5 * (double)wsc[3 + 2];  // halved: doubled-scale weights
#pragma unroll
  for (int mi = 0; mi < 4; ++mi) {
#pragma unroll
    for (int rg = 0; rg < 4; ++rg) {
      int grow = m0 + wr * 64 + mi * 16 + lgp * 4 + rg;
      double sc = ahd[grow] * md;
#pragma unroll
      for (int ni = 0; ni < 2; ++ni) {
        int gcol = n0 + wc * 32 + ni * 16 + l15;
        out[(size_t)grow * HDIM + gcol] = (float)((double)acc[mi][ni][rg] * sc);
      }
    }
  }
}

extern "C" void kernel_launch(void* const* d_in, const int* in_sizes, int n_in,
                              void* d_out, int out_size, void* d_ws, size_t ws_size,
                              hipStream_t stream) {
  const float* x   = (const float*)d_in[0];
  const float* wg  = (const float*)d_in[1];
  const float* wu  = (const float*)d_in[2];
  const float* wd  = (const float*)d_in[3];
  const float* lnw = (const float*)d_in[4];
  float* out = (float*)d_out;
  char* ws = (char*)d_ws;

  size_t off = 0;
  auto alloc = [&](size_t b) { size_t o = off; off += (b + 255) & ~(size_t)255; return o; };
  size_t o_wsc  = alloc(8 * 4);                 // s32[3], fl32(1/s)[3]
  size_t o_part = alloc(3 * NBLK * 4);
  size_t o_axd  = alloc((size_t)TOKENS * 8);
  size_t o_ahd  = alloc((size_t)TOKENS * 8);
  size_t o_qx   = alloc((size_t)TOKENS * HDIM);
  size_t o_qg   = alloc((size_t)IDIM * HDIM);   // qh later overlays qg
  size_t o_qu   = alloc((size_t)IDIM * HDIM);
  size_t o_qd   = alloc((size_t)HDIM * IDIM);
  size_t o_h    = alloc((size_t)TOKENS * IDIM * 4);
  (void)ws_size; (void)in_sizes; (void)n_in; (void)out_size; (void)o_qu;

  float* wsc  = (float*)(ws + o_wsc);
  float* part = (float*)(ws + o_part);
  double* axd = (double*)(ws + o_axd);
  double* ahd = (double*)(ws + o_ahd);
  int8_t* qx  = (int8_t*)(ws + o_qx);
  int8_t* qg  = (int8_t*)(ws + o_qg);
  int8_t* qu  = (int8_t*)(ws + o_qu);
  int8_t* qd  = (int8_t*)(ws + o_qd);
  int8_t* qh  = (int8_t*)(ws + o_qg);  // overlay: qg/qu dead after gemm1
  float* h    = (float*)(ws + o_h);

  wsum_leaf<<<dim3(NBLK, 3), 256, 0, stream>>>(wg, wu, wd, part);
  wsum_final<<<3, 256, 0, stream>>>(part, wsc);
  wquant_kernel<<<dim3(1024, 3), 256, 0, stream>>>(wg, wu, wd, wsc, qg, qu, qd);
  xquant_kernel<<<TOKENS, 256, 0, stream>>>(x, qx, axd);
  gemm1_kernel<<<dim3(IDIM / 128, TOKENS / 256), 512, 0, stream>>>(qx, qg, qu, wsc, axd, h);
  hquant_kernel<<<TOKENS, 256, 0, stream>>>(h, lnw, ahd, qh);
  gemm2_kernel<<<dim3(HDIM / 128, TOKENS / 128), 512, 3 * 16384, stream>>>(qh, qd, wsc, ahd, out);
}